// Round 13
// baseline (467.894 us; speedup 1.0000x reference)
//
#include <hip/hip_runtime.h>

#define Bz 256
#define Sz 64
#define Hz 256
#define Vz 32000
#define Tz 11
#define Mz (Bz*Tz)   // 2816

typedef __attribute__((ext_vector_type(8))) short bf16x8;
typedef __attribute__((ext_vector_type(4))) float f32x4;

__device__ __forceinline__ float blo(unsigned int u){ return __builtin_bit_cast(float, u<<16); }
__device__ __forceinline__ float bhi(unsigned int u){ return __builtin_bit_cast(float, u & 0xffff0000u); }
__device__ __forceinline__ unsigned short f2bf(float f){
  unsigned int x = __builtin_bit_cast(unsigned int, f);
  return (unsigned short)((x + 0x7fffu + ((x>>16)&1u)) >> 16);
}
__device__ __forceinline__ float bf2f(unsigned short u){ return __builtin_bit_cast(float, ((unsigned int)u)<<16); }
__device__ __forceinline__ float ftanh(float x){ float e = __expf(2.f*x); return 1.f - 2.f/(e+1.f); }

__device__ __forceinline__ float dot8(uint4 wv, const float* base){
  float4 h0 = *(const float4*)(base);
  float4 h1 = *(const float4*)(base+4);
  return blo(wv.x)*h0.x + bhi(wv.x)*h0.y + blo(wv.y)*h0.z + bhi(wv.y)*h0.w
       + blo(wv.z)*h1.x + bhi(wv.z)*h1.y + blo(wv.w)*h1.z + bhi(wv.w)*h1.w;
}

// async global->LDS, 16B per lane; LDS dest is wave-uniform base + lane*16
__device__ __forceinline__ void gll16(const unsigned short* g, unsigned short* l){
  __builtin_amdgcn_global_load_lds(
      (const __attribute__((address_space(1))) unsigned int*)g,
      (__attribute__((address_space(3))) unsigned int*)l, 16, 0, 0);
}

// ---------------- prep: small-weight pack + E + uk + W2E ----------------
// Packed layout for recurrence weights: p[(jb*256 + k)*8 + e] = W[k][jb*8+e]
// W2E[b,s,k] = enc[b,s,:] . Wih2[k,:]  (step-invariant; replaces the per-step
// Wih2.ctx GEMV in k_rnn via linearity: Wih2.ctx = sum_s attn_s * W2E[b,s,:])
__global__ __launch_bounds__(256) void k_prep(
    const float* __restrict__ Wa,
    const float* __restrict__ Wih, const float* __restrict__ Whh,
    const int* __restrict__ target, const float* __restrict__ embedding,
    const float* __restrict__ b_ih,
    const float* __restrict__ enc, const float* __restrict__ Ua,
    const float* __restrict__ bua,
    unsigned short* __restrict__ wa_p, unsigned short* __restrict__ whh_p,
    float* __restrict__ E, unsigned short* __restrict__ uk_b,
    unsigned short* __restrict__ w2e_b){
  __shared__ float rows[16][Hz];
  int tid = threadIdx.x;
  int bid = blockIdx.x;
  if (bid < 256){
    // small recurrence weights: bf16 + coalesced pack (Wa, Whh only)
    int i = bid*256 + tid;      // 0..65535
    int k = i>>8, j = i&255;
    int p = ((j>>3)*256 + k)*8 + (j&7);
    wa_p[p]   = f2bf(Wa[i]);
    whh_p[p]  = f2bf(Whh[i]);
  } else if (bid < 256+176){
    // E[m][k] = b_ih[k] + emb(tok_m) . W_ih[k][0:256]
    int m0 = (bid-256)*16;
    for (int r=0;r<16;r++){
      int m = m0 + r; int b = m/11, t = m - b*11;
      int tok = (t==0) ? 0 : target[b*11 + (t-1)];
      rows[r][tid] = embedding[(size_t)tok*Hz + tid];
    }
    __syncthreads();
    float acc[16];
    #pragma unroll
    for (int r=0;r<16;r++) acc[r]=0.f;
    const float* wrow = Wih + tid*512;
    for (int j4=0;j4<64;j4++){
      float4 w = *(const float4*)(wrow + j4*4);
      #pragma unroll
      for (int r=0;r<16;r++){
        float4 e = *(const float4*)(&rows[r][j4*4]);
        acc[r] += w.x*e.x + w.y*e.y + w.z*e.z + w.w*e.w;
      }
    }
    float bi = b_ih[tid];
    for (int r=0;r<16;r++) E[(m0+r)*Hz + tid] = acc[r] + bi;
  } else if (bid < 256+176+1024){
    // uk[b,s,k] = bua[k] + enc[b,s,:] . Ua[k,:]  (bf16 out)
    int r0 = (bid-(256+176))*16;
    for (int r=0;r<16;r++) rows[r][tid] = enc[(size_t)(r0+r)*Hz + tid];
    __syncthreads();
    float acc[16];
    #pragma unroll
    for (int r=0;r<16;r++) acc[r]=0.f;
    const float* wrow = Ua + tid*Hz;
    for (int j4=0;j4<64;j4++){
      float4 w = *(const float4*)(wrow + j4*4);
      #pragma unroll
      for (int r=0;r<16;r++){
        float4 e = *(const float4*)(&rows[r][j4*4]);
        acc[r] += w.x*e.x + w.y*e.y + w.z*e.z + w.w*e.w;
      }
    }
    float bk = bua[tid];
    for (int r=0;r<16;r++) uk_b[(size_t)(r0+r)*Hz + tid] = f2bf(acc[r] + bk);
  } else {
    // W2E[b,s,k] = enc[b,s,:] . Wih2[k,:]  (bf16 out; Wih2[k][j] = Wih[k][256+j])
    int r0 = (bid-(256+176+1024))*16;
    for (int r=0;r<16;r++) rows[r][tid] = enc[(size_t)(r0+r)*Hz + tid];
    __syncthreads();
    float acc[16];
    #pragma unroll
    for (int r=0;r<16;r++) acc[r]=0.f;
    const float* wrow = Wih + tid*512 + 256;
    for (int j4=0;j4<64;j4++){
      float4 w = *(const float4*)(wrow + j4*4);
      #pragma unroll
      for (int r=0;r<16;r++){
        float4 e = *(const float4*)(&rows[r][j4*4]);
        acc[r] += w.x*e.x + w.y*e.y + w.z*e.z + w.w*e.w;
      }
    }
    for (int r=0;r<16;r++) w2e_b[(size_t)(r0+r)*Hz + tid] = f2bf(acc[r]);
  }
}

// ---------------- recurrence (blocks 0..255, 512 thr) + Wout conversion (256..1279) ----
// Restructured: ctx phase and Wih2 GEMV removed via W2E linearity. Per step:
// A (Wa.h, Whh.h GEMVs) -> B scores -> C softmax -> D' hh2 = sum_s attn*W2E (LDS-only)
// -> combine. 6 barriers/step (was 8), 2/3 the weight traffic, no enc staging.
// Register structure of surviving loops identical to R11 (proven no-spill).
__global__ __launch_bounds__(512) __attribute__((amdgpu_waves_per_eu(2,4)))
void k_rnn(
    const float* __restrict__ ench,
    const float* __restrict__ ba, const float* __restrict__ Va,
    const float* __restrict__ bva, const float* __restrict__ b_hh,
    const unsigned short* __restrict__ uk_b, const unsigned short* __restrict__ wa_p,
    const unsigned short* __restrict__ whh_p, const unsigned short* __restrict__ w2e_b,
    const float* __restrict__ E, unsigned short* __restrict__ hs_b,
    float* __restrict__ out_hlast, float* __restrict__ out_attn,
    const float* __restrict__ Wout, unsigned short* __restrict__ wout_b){
  __shared__ __align__(16) unsigned short uk_lds[Sz][Hz];   // 32KB
  __shared__ __align__(16) unsigned short w2e_lds[Sz][Hz];  // 32KB
  __shared__ __align__(16) float h_lds[Hz];
  __shared__ __align__(16) float q_lds[Hz];
  __shared__ __align__(16) float hh_lds[Hz];
  __shared__ __align__(16) float redq[2][Hz];               // 2KB
  __shared__ __align__(16) float redh[2][Hz];               // 2KB
  __shared__ float sc_lds[Sz];
  __shared__ float attn_lds[Sz];
  int tid = threadIdx.x;

  if (blockIdx.x >= Bz){
    // ---- Wout f32 -> bf16 streaming conversion (1024 blocks x 512 thr) ----
    int i = (blockIdx.x - Bz)*512 + tid;
    const int stride = 1024*512;
    for (int idx = i; idx < Vz*Hz; idx += stride) wout_b[idx] = f2bf(Wout[idx]);
    return;
  }

  int b = blockIdx.x;
  int k = tid & 255, qd = tid >> 8;       // output index, K-half (0/1)
  int lane = tid & 63, wv = tid >> 6;     // lane, wave 0..7
  const int rot = (b & 3) << 2;           // stagger offset: {0,4,8,12} jb-groups

  { // stage uk[b] and W2E[b] (bf16, 32KB each) into LDS
    const uint4* src1 = (const uint4*)(uk_b  + (size_t)b*Sz*Hz);
    const uint4* src2 = (const uint4*)(w2e_b + (size_t)b*Sz*Hz);
    uint4* dst1 = (uint4*)(&uk_lds[0][0]);
    uint4* dst2 = (uint4*)(&w2e_lds[0][0]);
    #pragma unroll
    for (int i=0;i<4;i++){
      dst1[i*512+tid] = src1[i*512+tid];
      dst2[i*512+tid] = src2[i*512+tid];
    }
  }
  if (tid < Hz) h_lds[tid] = ench[b*Hz + tid];
  float va_r[4];
  #pragma unroll
  for (int c=0;c<4;c++) va_r[c] = Va[lane + 64*c];
  float ba_k = ba[k], bhh_k = b_hh[k], bva_s = bva[0];

  // packed weight pointers, pre-offset: element (jb_local) at [jb*256 + k]
  const uint4* wap = (const uint4*)(wa_p)  + (size_t)qd*16*256 + k;
  const uint4* whp = (const uint4*)(whh_p) + (size_t)qd*16*256 + k;
  __syncthreads();

  for (int t=0; t<Tz; t++){
    int m = b*Tz + t;
    const float* hb = &h_lds[qd*128];
    // ---- phase A: both h-GEMVs (q = Wa.h, hh = Whh.h) — separate loops (no spill),
    //      jb-group order rotated per block to spread L2 line pressure
    {
      float a0=0.f, a1=0.f, a2=0.f, a3=0.f;
      #pragma unroll 2
      for (int jx=0;jx<16;jx+=4){
        int jj = (jx + rot) & 15;
        uint4 w0=wap[(jj+0)*256], w1=wap[(jj+1)*256], w2=wap[(jj+2)*256], w3=wap[(jj+3)*256];
        a0 += dot8(w0, hb + jj*8 +  0);
        a1 += dot8(w1, hb + jj*8 +  8);
        a2 += dot8(w2, hb + jj*8 + 16);
        a3 += dot8(w3, hb + jj*8 + 24);
      }
      redq[qd][k] = (a0+a1) + (a2+a3);
      float b0=0.f, b1=0.f, b2=0.f, b3=0.f;
      #pragma unroll 2
      for (int jx=0;jx<16;jx+=4){
        int jj = (jx + rot) & 15;
        uint4 w0=whp[(jj+0)*256], w1=whp[(jj+1)*256], w2=whp[(jj+2)*256], w3=whp[(jj+3)*256];
        b0 += dot8(w0, hb + jj*8 +  0);
        b1 += dot8(w1, hb + jj*8 +  8);
        b2 += dot8(w2, hb + jj*8 + 16);
        b3 += dot8(w3, hb + jj*8 + 24);
      }
      redh[qd][k] = (b0+b1) + (b2+b3);
    }
    __syncthreads();
    if (qd == 0) q_lds[k]  = redq[0][k] + redq[1][k] + ba_k;
    else         hh_lds[k] = redh[0][k] + redh[1][k];
    __syncthreads();
    // ---- phase B: scores[s]; wave wv handles 8 s values
    {
      float ql[4];
      #pragma unroll
      for (int c=0;c<4;c++) ql[c] = q_lds[lane + 64*c];
      #pragma unroll
      for (int si=0; si<8; si++){
        int s = wv*8 + si;
        float p = 0.f;
        #pragma unroll
        for (int c=0;c<4;c++){
          float u = bf2f(uk_lds[s][lane + 64*c]);
          p += ftanh(ql[c] + u) * va_r[c];
        }
        #pragma unroll
        for (int off=1; off<64; off<<=1) p += __shfl_xor(p, off, 64);
        if (lane==0) sc_lds[s] = p + bva_s;
      }
    }
    __syncthreads();
    // ---- phase C: softmax over s (each wave redundant; 1 exp/thread)
    {
      float sv = sc_lds[lane];
      float mx = sv;
      #pragma unroll
      for (int off=1; off<64; off<<=1) mx = fmaxf(mx, __shfl_xor(mx, off, 64));
      float e = __expf(sv - mx);
      float sum = e;
      #pragma unroll
      for (int off=1; off<64; off<<=1) sum += __shfl_xor(sum, off, 64);
      float a = e / sum;
      if (wv == 0){
        attn_lds[lane] = a;
        out_attn[(size_t)m*Sz + lane] = a;
      }
    }
    __syncthreads();
    // ---- phase D': hh2[k] = sum_s attn[s] * W2E[s][k]  (s-split over qd; LDS-only)
    {
      float c0=0.f, c1=0.f;
      #pragma unroll
      for (int i=0;i<32;i+=2){
        int s = qd*32 + i;
        c0 += attn_lds[s]   * bf2f(w2e_lds[s][k]);
        c1 += attn_lds[s+1] * bf2f(w2e_lds[s+1][k]);
      }
      redq[qd][k] = c0 + c1;
    }
    __syncthreads();
    if (qd == 0){
      float acc = E[(size_t)m*Hz+k] + bhh_k + hh_lds[k] + redq[0][k] + redq[1][k];
      float hn = ftanh(acc);
      h_lds[k] = hn;
      hs_b[(size_t)m*Hz + k] = f2bf(hn);
      if (t==Tz-1) out_hlast[b*Hz + k] = hn;
    }
    __syncthreads();
  }
}

// ---------------- big GEMM: C[m][v] = hs[m,:].Wout[v,:] + b_out[v] ----------------
// R11 form (frozen): BK=64, gll16 staging, XCD-chunked bijective remap (bn-major),
// kt rotation by bm to stagger panel-sharing blocks' K-step order.
__global__ __launch_bounds__(256) void k_gemm(
    const unsigned short* __restrict__ Ab, const unsigned short* __restrict__ Bb,
    const float* __restrict__ b_out, const float* __restrict__ lse,
    float* __restrict__ out, float* __restrict__ partials){
  __shared__ __align__(16) unsigned short As[128*64];
  __shared__ __align__(16) unsigned short Bs[128*64];
  int tid = threadIdx.x;
  int fid = blockIdx.x;               // 0..5499
  int xcd = fid & 7, wu = fid >> 3;   // hardware round-robins consecutive ids over 8 XCDs
  int wid = (xcd < 4 ? xcd*688 : 4*688 + (xcd-4)*687) + wu;  // bijective chunked
  int bn = wid / 22;                  // 0..249  (bn-major: 22 consecutive wids share bn)
  int bm = wid - bn*22;               // 0..21
  int m0 = bm*128, n0 = bn*128;
  int w = tid>>6, lane = tid&63;
  int wm = w>>1, wn = w&1;
  f32x4 acc[4][4];
  #pragma unroll
  for (int i=0;i<4;i++)
    #pragma unroll
    for (int j=0;j<4;j++) acc[i][j] = (f32x4){0.f,0.f,0.f,0.f};

  for (int ktx=0; ktx<4; ktx++){
    int kt = (ktx + bm) & 3;          // staggered K-step order
    __syncthreads();
    // async stage: per wave-instr, 64 lanes x 16B -> 1KB contiguous LDS
    #pragma unroll
    for (int i=0;i<4;i++){
      int chunk = i*256 + tid;          // = (i*256 + w*64) + lane
      int row = chunk>>3, c8 = chunk&7;
      gll16(Ab + (size_t)(m0+row)*Hz + kt*64 + c8*8, &As[(i*256 + w*64)*8]);
      gll16(Bb + (size_t)(n0+row)*Hz + kt*64 + c8*8, &Bs[(i*256 + w*64)*8]);
    }
    __syncthreads();
    #pragma unroll
    for (int ks=0; ks<2; ks++){
      bf16x8 af[4], bg[4];
      #pragma unroll
      for (int i=0;i<4;i++){
        int row = wm*64 + i*16 + (lane&15);
        af[i] = *(const bf16x8*)(&As[row*64 + ks*32 + (lane>>4)*8]);
      }
      #pragma unroll
      for (int j=0;j<4;j++){
        int row = wn*64 + j*16 + (lane&15);
        bg[j] = *(const bf16x8*)(&Bs[row*64 + ks*32 + (lane>>4)*8]);
      }
      #pragma unroll
      for (int i=0;i<4;i++)
        #pragma unroll
        for (int j=0;j<4;j++)
          acc[i][j] = __builtin_amdgcn_mfma_f32_16x16x32_bf16(af[i], bg[j], acc[i][j], 0,0,0);
    }
  }
  int col_l = lane & 15, rgrp = lane >> 4;
  if (lse == nullptr){
    #pragma unroll
    for (int i=0;i<4;i++){
      int rowbase = m0 + wm*64 + i*16 + rgrp*4;
      #pragma unroll
      for (int r=0;r<4;r++){
        float se = 0.f;
        #pragma unroll
        for (int j=0;j<4;j++){
          int col = n0 + wn*64 + j*16 + col_l;
          se += __expf(acc[i][j][r] + b_out[col]);
        }
        se += __shfl_xor(se,1,64); se += __shfl_xor(se,2,64);
        se += __shfl_xor(se,4,64); se += __shfl_xor(se,8,64);
        if (col_l == 0) partials[(size_t)(bn*2+wn)*Mz + rowbase + r] = se;
      }
    }
  } else {
    #pragma unroll
    for (int i=0;i<4;i++){
      int rowbase = m0 + wm*64 + i*16 + rgrp*4;
      #pragma unroll
      for (int r=0;r<4;r++){
        float l = lse[rowbase + r];
        #pragma unroll
        for (int j=0;j<4;j++){
          int col = n0 + wn*64 + j*16 + col_l;
          out[(size_t)(rowbase+r)*Vz + col] = acc[i][j][r] + b_out[col] - l;
        }
      }
    }
  }
}

__global__ __launch_bounds__(256) void k_lse(const float* __restrict__ partials,
                                             float* __restrict__ lse){
  int m = blockIdx.x*256 + threadIdx.x;
  if (m < Mz){
    float s = 0.f;
    for (int c=0;c<500;c++) s += partials[(size_t)c*Mz + m];
    lse[m] = logf(s);
  }
}

extern "C" void kernel_launch(void* const* d_in, const int* in_sizes, int n_in,
                              void* d_out, int out_size, void* d_ws, size_t ws_size,
                              hipStream_t stream) {
  const float* enc   = (const float*)d_in[0];
  const float* ench  = (const float*)d_in[1];
  const int*   target= (const int*)d_in[2];
  const float* emb   = (const float*)d_in[3];
  const float* Wa    = (const float*)d_in[4];
  const float* ba    = (const float*)d_in[5];
  const float* Ua    = (const float*)d_in[6];
  const float* bua   = (const float*)d_in[7];
  const float* Va    = (const float*)d_in[8];
  const float* bva   = (const float*)d_in[9];
  const float* Wih   = (const float*)d_in[10];
  const float* bih   = (const float*)d_in[11];
  const float* Whh   = (const float*)d_in[12];
  const float* bhh   = (const float*)d_in[13];
  const float* Wout  = (const float*)d_in[14];
  const float* bout  = (const float*)d_in[15];

  float* out = (float*)d_out;
  float* out_logits = out;                              // [2816][32000]
  float* out_hlast  = out + (size_t)Mz*Vz;              // [256][256]
  float* out_attn   = out_hlast + Bz*Hz;                // [2816][64]

  // ws layout: bf16 W_out + small packed bf16 weights + hs + lse
  char* ws = (char*)d_ws;
  unsigned short* wout_b = (unsigned short*)(ws);                 // 16,384,000 B
  unsigned short* wa_p   = (unsigned short*)(ws + 16384000);      // 131,072
  unsigned short* whh_p  = (unsigned short*)(ws + 16515072);      // 131,072
  unsigned short* hs_b   = (unsigned short*)(ws + 16777216);      // 1,441,792
  float*          lse    = (float*)(ws + 18219008);               // 11,264

  // bulky transients live in the (not-yet-written) logits region of d_out:
  // uk (8,388,608) | E (2,883,584) | partials (5,632,000) | W2E (8,388,608)
  // — all dead before pass-2 writes
  char* sc = (char*)d_out;
  unsigned short* uk_b     = (unsigned short*)(sc);
  float*          E        = (float*)(sc + 8388608);
  float*          partials = (float*)(sc + 11272192);
  unsigned short* w2e_b    = (unsigned short*)(sc + 16904192);

  k_prep <<<256+176+1024+1024, 256, 0, stream>>>(Wa, Wih, Whh,
                                            target, emb, bih, enc, Ua, bua,
                                            wa_p, whh_p, E, uk_b, w2e_b);
  k_rnn  <<<Bz+1024, 512, 0, stream>>>(ench, ba, Va, bva, bhh,
                                       uk_b, wa_p, whh_p, w2e_b, E, hs_b,
                                       out_hlast, out_attn, Wout, wout_b);
  k_gemm <<<5500, 256, 0, stream>>>(hs_b, wout_b, bout, nullptr, out_logits, partials);
  k_lse  <<<11, 256, 0, stream>>>(partials, lse);
  k_gemm <<<5500, 256, 0, stream>>>(hs_b, wout_b, bout, lse, out_logits, partials);
}

// Round 14
// 399.269 us; speedup vs baseline: 1.1719x; 1.1719x over previous
//
#include <hip/hip_runtime.h>

#define Bz 256
#define Sz 64
#define Hz 256
#define Vz 32000
#define Tz 11
#define Mz (Bz*Tz)   // 2816

typedef __attribute__((ext_vector_type(8))) short bf16x8;
typedef __attribute__((ext_vector_type(4))) float f32x4;

__device__ __forceinline__ float blo(unsigned int u){ return __builtin_bit_cast(float, u<<16); }
__device__ __forceinline__ float bhi(unsigned int u){ return __builtin_bit_cast(float, u & 0xffff0000u); }
__device__ __forceinline__ unsigned short f2bf(float f){
  unsigned int x = __builtin_bit_cast(unsigned int, f);
  return (unsigned short)((x + 0x7fffu + ((x>>16)&1u)) >> 16);
}
__device__ __forceinline__ float bf2f(unsigned short u){ return __builtin_bit_cast(float, ((unsigned int)u)<<16); }
__device__ __forceinline__ float ftanh(float x){ float e = __expf(2.f*x); return 1.f - 2.f/(e+1.f); }

__device__ __forceinline__ float dot8(uint4 wv, const float* base){
  float4 h0 = *(const float4*)(base);
  float4 h1 = *(const float4*)(base+4);
  return blo(wv.x)*h0.x + bhi(wv.x)*h0.y + blo(wv.y)*h0.z + bhi(wv.y)*h0.w
       + blo(wv.z)*h1.x + bhi(wv.z)*h1.y + blo(wv.w)*h1.z + bhi(wv.w)*h1.w;
}

// async global->LDS, 16B per lane; LDS dest is wave-uniform base + lane*16
__device__ __forceinline__ void gll16(const unsigned short* g, unsigned short* l){
  __builtin_amdgcn_global_load_lds(
      (const __attribute__((address_space(1))) unsigned int*)g,
      (__attribute__((address_space(3))) unsigned int*)l, 16, 0, 0);
}

// ---------------- prep: small-weight pack + E + uk (R11 form) ----------------
// Packed layout for recurrence weights: p[(jb*256 + k)*8 + e] = W[k][jb*8+e]
__global__ __launch_bounds__(256) void k_prep(
    const float* __restrict__ Wa,
    const float* __restrict__ Wih, const float* __restrict__ Whh,
    const int* __restrict__ target, const float* __restrict__ embedding,
    const float* __restrict__ b_ih,
    const float* __restrict__ enc, const float* __restrict__ Ua,
    const float* __restrict__ bua,
    unsigned short* __restrict__ wa_p,
    unsigned short* __restrict__ wih2_p, unsigned short* __restrict__ whh_p,
    float* __restrict__ E, unsigned short* __restrict__ uk_b){
  __shared__ float rows[16][Hz];
  int tid = threadIdx.x;
  int bid = blockIdx.x;
  if (bid < 256){
    // small recurrence weights: bf16 + coalesced pack
    int i = bid*256 + tid;      // 0..65535
    int k = i>>8, j = i&255;
    int p = ((j>>3)*256 + k)*8 + (j&7);
    wa_p[p]   = f2bf(Wa[i]);
    whh_p[p]  = f2bf(Whh[i]);
    wih2_p[p] = f2bf(Wih[k*512 + 256 + j]);
  } else if (bid < 256+176){
    // E[m][k] = b_ih[k] + emb(tok_m) . W_ih[k][0:256]
    int m0 = (bid-256)*16;
    for (int r=0;r<16;r++){
      int m = m0 + r; int b = m/11, t = m - b*11;
      int tok = (t==0) ? 0 : target[b*11 + (t-1)];
      rows[r][tid] = embedding[(size_t)tok*Hz + tid];
    }
    __syncthreads();
    float acc[16];
    #pragma unroll
    for (int r=0;r<16;r++) acc[r]=0.f;
    const float* wrow = Wih + tid*512;
    for (int j4=0;j4<64;j4++){
      float4 w = *(const float4*)(wrow + j4*4);
      #pragma unroll
      for (int r=0;r<16;r++){
        float4 e = *(const float4*)(&rows[r][j4*4]);
        acc[r] += w.x*e.x + w.y*e.y + w.z*e.z + w.w*e.w;
      }
    }
    float bi = b_ih[tid];
    for (int r=0;r<16;r++) E[(m0+r)*Hz + tid] = acc[r] + bi;
  } else {
    // uk[b,s,k] = bua[k] + enc[b,s,:] . Ua[k,:]  (bf16 out)
    int r0 = (bid-(256+176))*16;
    for (int r=0;r<16;r++) rows[r][tid] = enc[(size_t)(r0+r)*Hz + tid];
    __syncthreads();
    float acc[16];
    #pragma unroll
    for (int r=0;r<16;r++) acc[r]=0.f;
    const float* wrow = Ua + tid*Hz;
    for (int j4=0;j4<64;j4++){
      float4 w = *(const float4*)(wrow + j4*4);
      #pragma unroll
      for (int r=0;r<16;r++){
        float4 e = *(const float4*)(&rows[r][j4*4]);
        acc[r] += w.x*e.x + w.y*e.y + w.z*e.z + w.w*e.w;
      }
    }
    float bk = bua[tid];
    for (int r=0;r<16;r++) uk_b[(size_t)(r0+r)*Hz + tid] = f2bf(acc[r] + bk);
  }
}

// ---------------- recurrence (blocks 0..255, 512 thr) + Wout conversion (256..1279) ----
// R11 base + two latency micro-opts:
//  (1) inline q/hh reductions (one less barrier/step, two fewer LDS round-trips)
//  (2) E[m,k] prefetched at end of phase A, consumed in the combine (~300cy hidden)
// Register structure of GEMV loops identical to R11 (proven no-spill).
__global__ __launch_bounds__(512) __attribute__((amdgpu_waves_per_eu(2,4)))
void k_rnn(
    const float* __restrict__ enc, const float* __restrict__ ench,
    const float* __restrict__ ba, const float* __restrict__ Va,
    const float* __restrict__ bva, const float* __restrict__ b_hh,
    const unsigned short* __restrict__ uk_b, const unsigned short* __restrict__ wa_p,
    const unsigned short* __restrict__ wih2_p, const unsigned short* __restrict__ whh_p,
    const float* __restrict__ E, unsigned short* __restrict__ hs_b,
    float* __restrict__ out_hlast, float* __restrict__ out_attn,
    const float* __restrict__ Wout, unsigned short* __restrict__ wout_b){
  __shared__ __align__(16) unsigned short uk_lds[Sz][Hz];   // 32KB
  __shared__ __align__(16) unsigned short enc_lds[Sz][Hz];  // 32KB
  __shared__ __align__(16) float h_lds[Hz];
  __shared__ __align__(16) float ctx_lds[Hz];
  __shared__ __align__(16) float redq[2][Hz];               // 2KB (q partials, then ctx partials)
  __shared__ __align__(16) float redh_a[2][Hz];             // 2KB (Whh.h partials, live whole step)
  __shared__ __align__(16) float redh[2][Hz];               // 2KB (Wih2.ctx partials)
  __shared__ float sc_lds[Sz];
  __shared__ float attn_lds[Sz];
  int tid = threadIdx.x;

  if (blockIdx.x >= Bz){
    // ---- Wout f32 -> bf16 streaming conversion (1024 blocks x 512 thr) ----
    int i = (blockIdx.x - Bz)*512 + tid;
    const int stride = 1024*512;
    for (int idx = i; idx < Vz*Hz; idx += stride) wout_b[idx] = f2bf(Wout[idx]);
    return;
  }

  int b = blockIdx.x;
  int k = tid & 255, qd = tid >> 8;       // output index, K-half (0/1)
  int lane = tid & 63, wv = tid >> 6;     // lane, wave 0..7
  const int rot = (b & 3) << 2;           // stagger offset: {0,4,8,12} jb-groups

  { // stage uk[b] (bf16, 32KB) into LDS
    const uint4* src = (const uint4*)(uk_b + (size_t)b*Sz*Hz);
    uint4* dst = (uint4*)(&uk_lds[0][0]);
    #pragma unroll
    for (int i=0;i<4;i++) dst[i*512+tid] = src[i*512+tid];
  }
  { // stage enc[b] f32 -> bf16 LDS
    const float4* src = (const float4*)(enc + (size_t)b*Sz*Hz);
    #pragma unroll
    for (int i=0;i<8;i++){
      int idx = i*512 + tid;              // 0..4095 float4s
      float4 v = src[idx];
      ushort4 p; p.x=f2bf(v.x); p.y=f2bf(v.y); p.z=f2bf(v.z); p.w=f2bf(v.w);
      *(ushort4*)((unsigned short*)(&enc_lds[0][0]) + idx*4) = p;
    }
  }
  if (tid < Hz) h_lds[tid] = ench[b*Hz + tid];
  float va_r[4], ba4[4];
  #pragma unroll
  for (int c=0;c<4;c++){ va_r[c] = Va[lane + 64*c]; ba4[c] = ba[lane + 64*c]; }
  float bhh_k = b_hh[k], bva_s = bva[0];

  // packed weight pointers, pre-offset: element (jb_local) at [jb*256 + k]
  const uint4* wap = (const uint4*)(wa_p)   + (size_t)qd*16*256 + k;
  const uint4* whp = (const uint4*)(whh_p)  + (size_t)qd*16*256 + k;
  const uint4* w2p = (const uint4*)(wih2_p) + (size_t)qd*16*256 + k;
  __syncthreads();

  for (int t=0; t<Tz; t++){
    int m = b*Tz + t;
    const float* hb = &h_lds[qd*128];
    // ---- phase A: both h-GEMVs (q = Wa.h, hh = Whh.h) — separate loops (no spill),
    //      jb-group order rotated per block to spread L2 line pressure
    {
      float a0=0.f, a1=0.f, a2=0.f, a3=0.f;
      #pragma unroll 2
      for (int jx=0;jx<16;jx+=4){
        int jj = (jx + rot) & 15;
        uint4 w0=wap[(jj+0)*256], w1=wap[(jj+1)*256], w2=wap[(jj+2)*256], w3=wap[(jj+3)*256];
        a0 += dot8(w0, hb + jj*8 +  0);
        a1 += dot8(w1, hb + jj*8 +  8);
        a2 += dot8(w2, hb + jj*8 + 16);
        a3 += dot8(w3, hb + jj*8 + 24);
      }
      redq[qd][k] = (a0+a1) + (a2+a3);
      float b0=0.f, b1=0.f, b2=0.f, b3=0.f;
      #pragma unroll 2
      for (int jx=0;jx<16;jx+=4){
        int jj = (jx + rot) & 15;
        uint4 w0=whp[(jj+0)*256], w1=whp[(jj+1)*256], w2=whp[(jj+2)*256], w3=whp[(jj+3)*256];
        b0 += dot8(w0, hb + jj*8 +  0);
        b1 += dot8(w1, hb + jj*8 +  8);
        b2 += dot8(w2, hb + jj*8 + 16);
        b3 += dot8(w3, hb + jj*8 + 24);
      }
      redh_a[qd][k] = (b0+b1) + (b2+b3);
    }
    // E-prefetch: consumed 5 phases later in the combine
    float e_pre = E[(size_t)m*Hz + k];
    __syncthreads();
    // ---- phase B: scores[s]; q reduction inlined (no intermediate barrier)
    {
      float ql[4];
      #pragma unroll
      for (int c=0;c<4;c++){
        int p = lane + 64*c;
        ql[c] = redq[0][p] + redq[1][p] + ba4[c];
      }
      #pragma unroll
      for (int si=0; si<8; si++){
        int s = wv*8 + si;
        float p = 0.f;
        #pragma unroll
        for (int c=0;c<4;c++){
          float u = bf2f(uk_lds[s][lane + 64*c]);
          p += ftanh(ql[c] + u) * va_r[c];
        }
        #pragma unroll
        for (int off=1; off<64; off<<=1) p += __shfl_xor(p, off, 64);
        if (lane==0) sc_lds[s] = p + bva_s;
      }
    }
    __syncthreads();
    // ---- phase C: softmax over s (each wave redundant; 1 exp/thread)
    {
      float sv = sc_lds[lane];
      float mx = sv;
      #pragma unroll
      for (int off=1; off<64; off<<=1) mx = fmaxf(mx, __shfl_xor(mx, off, 64));
      float e = __expf(sv - mx);
      float sum = e;
      #pragma unroll
      for (int off=1; off<64; off<<=1) sum += __shfl_xor(sum, off, 64);
      float a = e / sum;
      if (wv == 0){
        attn_lds[lane] = a;
        out_attn[(size_t)m*Sz + lane] = a;
      }
    }
    __syncthreads();
    // ---- phase D: ctx[k] = sum_s attn[s]*enc[b,s,k]  (s-split over qd)
    {
      float c0=0.f, c1=0.f;
      #pragma unroll
      for (int i=0;i<32;i+=2){
        int s = qd*32 + i;
        c0 += attn_lds[s]   * bf2f(enc_lds[s][k]);
        c1 += attn_lds[s+1] * bf2f(enc_lds[s+1][k]);
      }
      redq[qd][k] = c0 + c1;
    }
    __syncthreads();
    if (qd == 0) ctx_lds[k] = redq[0][k] + redq[1][k];
    __syncthreads();
    // ---- phase E: Wih2.ctx (rotated)
    {
      const float* cb = &ctx_lds[qd*128];
      float a0=0.f, a1=0.f, a2=0.f, a3=0.f;
      #pragma unroll 2
      for (int jx=0;jx<16;jx+=4){
        int jj = (jx + rot) & 15;
        uint4 w0=w2p[(jj+0)*256], w1=w2p[(jj+1)*256], w2=w2p[(jj+2)*256], w3=w2p[(jj+3)*256];
        a0 += dot8(w0, cb + jj*8 +  0);
        a1 += dot8(w1, cb + jj*8 +  8);
        a2 += dot8(w2, cb + jj*8 + 16);
        a3 += dot8(w3, cb + jj*8 + 24);
      }
      redh[qd][k] = (a0+a1) + (a2+a3);
    }
    __syncthreads();
    // ---- combine: hh reduction inlined (redh_a from phase A still live)
    if (qd == 0){
      float acc = e_pre + bhh_k
                + redh_a[0][k] + redh_a[1][k]
                + redh[0][k]   + redh[1][k];
      float hn = ftanh(acc);
      h_lds[k] = hn;
      hs_b[(size_t)m*Hz + k] = f2bf(hn);
      if (t==Tz-1) out_hlast[b*Hz + k] = hn;
    }
    __syncthreads();
  }
}

// ---------------- big GEMM: C[m][v] = hs[m,:].Wout[v,:] + b_out[v] ----------------
// R11 form (frozen): BK=64, gll16 staging, XCD-chunked bijective remap (bn-major),
// kt rotation by bm to stagger panel-sharing blocks' K-step order.
__global__ __launch_bounds__(256) void k_gemm(
    const unsigned short* __restrict__ Ab, const unsigned short* __restrict__ Bb,
    const float* __restrict__ b_out, const float* __restrict__ lse,
    float* __restrict__ out, float* __restrict__ partials){
  __shared__ __align__(16) unsigned short As[128*64];
  __shared__ __align__(16) unsigned short Bs[128*64];
  int tid = threadIdx.x;
  int fid = blockIdx.x;               // 0..5499
  int xcd = fid & 7, wu = fid >> 3;   // hardware round-robins consecutive ids over 8 XCDs
  int wid = (xcd < 4 ? xcd*688 : 4*688 + (xcd-4)*687) + wu;  // bijective chunked
  int bn = wid / 22;                  // 0..249  (bn-major: 22 consecutive wids share bn)
  int bm = wid - bn*22;               // 0..21
  int m0 = bm*128, n0 = bn*128;
  int w = tid>>6, lane = tid&63;
  int wm = w>>1, wn = w&1;
  f32x4 acc[4][4];
  #pragma unroll
  for (int i=0;i<4;i++)
    #pragma unroll
    for (int j=0;j<4;j++) acc[i][j] = (f32x4){0.f,0.f,0.f,0.f};

  for (int ktx=0; ktx<4; ktx++){
    int kt = (ktx + bm) & 3;          // staggered K-step order
    __syncthreads();
    // async stage: per wave-instr, 64 lanes x 16B -> 1KB contiguous LDS
    #pragma unroll
    for (int i=0;i<4;i++){
      int chunk = i*256 + tid;          // = (i*256 + w*64) + lane
      int row = chunk>>3, c8 = chunk&7;
      gll16(Ab + (size_t)(m0+row)*Hz + kt*64 + c8*8, &As[(i*256 + w*64)*8]);
      gll16(Bb + (size_t)(n0+row)*Hz + kt*64 + c8*8, &Bs[(i*256 + w*64)*8]);
    }
    __syncthreads();
    #pragma unroll
    for (int ks=0; ks<2; ks++){
      bf16x8 af[4], bg[4];
      #pragma unroll
      for (int i=0;i<4;i++){
        int row = wm*64 + i*16 + (lane&15);
        af[i] = *(const bf16x8*)(&As[row*64 + ks*32 + (lane>>4)*8]);
      }
      #pragma unroll
      for (int j=0;j<4;j++){
        int row = wn*64 + j*16 + (lane&15);
        bg[j] = *(const bf16x8*)(&Bs[row*64 + ks*32 + (lane>>4)*8]);
      }
      #pragma unroll
      for (int i=0;i<4;i++)
        #pragma unroll
        for (int j=0;j<4;j++)
          acc[i][j] = __builtin_amdgcn_mfma_f32_16x16x32_bf16(af[i], bg[j], acc[i][j], 0,0,0);
    }
  }
  int col_l = lane & 15, rgrp = lane >> 4;
  if (lse == nullptr){
    #pragma unroll
    for (int i=0;i<4;i++){
      int rowbase = m0 + wm*64 + i*16 + rgrp*4;
      #pragma unroll
      for (int r=0;r<4;r++){
        float se = 0.f;
        #pragma unroll
        for (int j=0;j<4;j++){
          int col = n0 + wn*64 + j*16 + col_l;
          se += __expf(acc[i][j][r] + b_out[col]);
        }
        se += __shfl_xor(se,1,64); se += __shfl_xor(se,2,64);
        se += __shfl_xor(se,4,64); se += __shfl_xor(se,8,64);
        if (col_l == 0) partials[(size_t)(bn*2+wn)*Mz + rowbase + r] = se;
      }
    }
  } else {
    #pragma unroll
    for (int i=0;i<4;i++){
      int rowbase = m0 + wm*64 + i*16 + rgrp*4;
      #pragma unroll
      for (int r=0;r<4;r++){
        float l = lse[rowbase + r];
        #pragma unroll
        for (int j=0;j<4;j++){
          int col = n0 + wn*64 + j*16 + col_l;
          out[(size_t)(rowbase+r)*Vz + col] = acc[i][j][r] + b_out[col] - l;
        }
      }
    }
  }
}

__global__ __launch_bounds__(256) void k_lse(const float* __restrict__ partials,
                                             float* __restrict__ lse){
  int m = blockIdx.x*256 + threadIdx.x;
  if (m < Mz){
    float s = 0.f;
    for (int c=0;c<500;c++) s += partials[(size_t)c*Mz + m];
    lse[m] = logf(s);
  }
}

extern "C" void kernel_launch(void* const* d_in, const int* in_sizes, int n_in,
                              void* d_out, int out_size, void* d_ws, size_t ws_size,
                              hipStream_t stream) {
  const float* enc   = (const float*)d_in[0];
  const float* ench  = (const float*)d_in[1];
  const int*   target= (const int*)d_in[2];
  const float* emb   = (const float*)d_in[3];
  const float* Wa    = (const float*)d_in[4];
  const float* ba    = (const float*)d_in[5];
  const float* Ua    = (const float*)d_in[6];
  const float* bua   = (const float*)d_in[7];
  const float* Va    = (const float*)d_in[8];
  const float* bva   = (const float*)d_in[9];
  const float* Wih   = (const float*)d_in[10];
  const float* bih   = (const float*)d_in[11];
  const float* Whh   = (const float*)d_in[12];
  const float* bhh   = (const float*)d_in[13];
  const float* Wout  = (const float*)d_in[14];
  const float* bout  = (const float*)d_in[15];

  float* out = (float*)d_out;
  float* out_logits = out;                              // [2816][32000]
  float* out_hlast  = out + (size_t)Mz*Vz;              // [256][256]
  float* out_attn   = out_hlast + Bz*Hz;                // [2816][64]

  // ws layout: bf16 W_out + small packed bf16 weights + hs + lse
  char* ws = (char*)d_ws;
  unsigned short* wout_b = (unsigned short*)(ws);                 // 16,384,000 B
  unsigned short* wa_p   = (unsigned short*)(ws + 16384000);      // 131,072
  unsigned short* wih2_p = (unsigned short*)(ws + 16515072);      // 131,072
  unsigned short* whh_p  = (unsigned short*)(ws + 16646144);      // 131,072
  unsigned short* hs_b   = (unsigned short*)(ws + 16777216);      // 1,441,792
  float*          lse    = (float*)(ws + 18219008);               // 11,264

  // bulky transients live in the (not-yet-written) logits region of d_out:
  // uk (8,388,608 B) | E (2,883,584 B) | partials (5,632,000 B) — all dead before pass-2 writes
  char* sc = (char*)d_out;
  unsigned short* uk_b     = (unsigned short*)(sc);
  float*          E        = (float*)(sc + 8388608);
  float*          partials = (float*)(sc + 11272192);

  k_prep <<<256+176+1024, 256, 0, stream>>>(Wa, Wih, Whh,
                                            target, emb, bih, enc, Ua, bua,
                                            wa_p, wih2_p, whh_p, E, uk_b);
  k_rnn  <<<Bz+1024, 512, 0, stream>>>(enc, ench, ba, Va, bva, bhh,
                                       uk_b, wa_p, wih2_p, whh_p, E, hs_b,
                                       out_hlast, out_attn, Wout, wout_b);
  k_gemm <<<5500, 256, 0, stream>>>(hs_b, wout_b, bout, nullptr, out_logits, partials);
  k_lse  <<<11, 256, 0, stream>>>(partials, lse);
  k_gemm <<<5500, 256, 0, stream>>>(hs_b, wout_b, bout, lse, out_logits, partials);
}

// Round 15
// 372.214 us; speedup vs baseline: 1.2571x; 1.0727x over previous
//
#include <hip/hip_runtime.h>

#define Bz 256
#define Sz 64
#define Hz 256
#define Vz 32000
#define Tz 11
#define Mz (Bz*Tz)   // 2816

typedef __attribute__((ext_vector_type(8))) short bf16x8;
typedef __attribute__((ext_vector_type(4))) float f32x4;

__device__ __forceinline__ float blo(unsigned int u){ return __builtin_bit_cast(float, u<<16); }
__device__ __forceinline__ float bhi(unsigned int u){ return __builtin_bit_cast(float, u & 0xffff0000u); }
__device__ __forceinline__ unsigned short f2bf(float f){
  unsigned int x = __builtin_bit_cast(unsigned int, f);
  return (unsigned short)((x + 0x7fffu + ((x>>16)&1u)) >> 16);
}
__device__ __forceinline__ float bf2f(unsigned short u){ return __builtin_bit_cast(float, ((unsigned int)u)<<16); }
__device__ __forceinline__ float ftanh(float x){ float e = __expf(2.f*x); return 1.f - 2.f/(e+1.f); }

__device__ __forceinline__ float dot8(uint4 wv, const float* base){
  float4 h0 = *(const float4*)(base);
  float4 h1 = *(const float4*)(base+4);
  return blo(wv.x)*h0.x + bhi(wv.x)*h0.y + blo(wv.y)*h0.z + bhi(wv.y)*h0.w
       + blo(wv.z)*h1.x + bhi(wv.z)*h1.y + blo(wv.w)*h1.z + bhi(wv.w)*h1.w;
}

// async global->LDS, 16B per lane; LDS dest is wave-uniform base + lane*16
__device__ __forceinline__ void gll16(const unsigned short* g, unsigned short* l){
  __builtin_amdgcn_global_load_lds(
      (const __attribute__((address_space(1))) unsigned int*)g,
      (__attribute__((address_space(3))) unsigned int*)l, 16, 0, 0);
}

// ---------------- prep: small-weight pack + E + uk (R11 form) ----------------
// Packed layout for recurrence weights: p[(jb*256 + k)*8 + e] = W[k][jb*8+e]
__global__ __launch_bounds__(256) void k_prep(
    const float* __restrict__ Wa,
    const float* __restrict__ Wih, const float* __restrict__ Whh,
    const int* __restrict__ target, const float* __restrict__ embedding,
    const float* __restrict__ b_ih,
    const float* __restrict__ enc, const float* __restrict__ Ua,
    const float* __restrict__ bua,
    unsigned short* __restrict__ wa_p,
    unsigned short* __restrict__ wih2_p, unsigned short* __restrict__ whh_p,
    float* __restrict__ E, unsigned short* __restrict__ uk_b){
  __shared__ float rows[16][Hz];
  int tid = threadIdx.x;
  int bid = blockIdx.x;
  if (bid < 256){
    // small recurrence weights: bf16 + coalesced pack
    int i = bid*256 + tid;      // 0..65535
    int k = i>>8, j = i&255;
    int p = ((j>>3)*256 + k)*8 + (j&7);
    wa_p[p]   = f2bf(Wa[i]);
    whh_p[p]  = f2bf(Whh[i]);
    wih2_p[p] = f2bf(Wih[k*512 + 256 + j]);
  } else if (bid < 256+176){
    // E[m][k] = b_ih[k] + emb(tok_m) . W_ih[k][0:256]
    int m0 = (bid-256)*16;
    for (int r=0;r<16;r++){
      int m = m0 + r; int b = m/11, t = m - b*11;
      int tok = (t==0) ? 0 : target[b*11 + (t-1)];
      rows[r][tid] = embedding[(size_t)tok*Hz + tid];
    }
    __syncthreads();
    float acc[16];
    #pragma unroll
    for (int r=0;r<16;r++) acc[r]=0.f;
    const float* wrow = Wih + tid*512;
    for (int j4=0;j4<64;j4++){
      float4 w = *(const float4*)(wrow + j4*4);
      #pragma unroll
      for (int r=0;r<16;r++){
        float4 e = *(const float4*)(&rows[r][j4*4]);
        acc[r] += w.x*e.x + w.y*e.y + w.z*e.z + w.w*e.w;
      }
    }
    float bi = b_ih[tid];
    for (int r=0;r<16;r++) E[(m0+r)*Hz + tid] = acc[r] + bi;
  } else {
    // uk[b,s,k] = bua[k] + enc[b,s,:] . Ua[k,:]  (bf16 out)
    int r0 = (bid-(256+176))*16;
    for (int r=0;r<16;r++) rows[r][tid] = enc[(size_t)(r0+r)*Hz + tid];
    __syncthreads();
    float acc[16];
    #pragma unroll
    for (int r=0;r<16;r++) acc[r]=0.f;
    const float* wrow = Ua + tid*Hz;
    for (int j4=0;j4<64;j4++){
      float4 w = *(const float4*)(wrow + j4*4);
      #pragma unroll
      for (int r=0;r<16;r++){
        float4 e = *(const float4*)(&rows[r][j4*4]);
        acc[r] += w.x*e.x + w.y*e.y + w.z*e.z + w.w*e.w;
      }
    }
    float bk = bua[tid];
    for (int r=0;r<16;r++) uk_b[(size_t)(r0+r)*Hz + tid] = f2bf(acc[r] + bk);
  }
}

// ---------------- recurrence (blocks 0..255, 512 thr) + Wout conversion (256..1279) ----
// R14 form (best): R11 + inlined q/hh reductions + E-prefetch. FROZEN.
__global__ __launch_bounds__(512) __attribute__((amdgpu_waves_per_eu(2,4)))
void k_rnn(
    const float* __restrict__ enc, const float* __restrict__ ench,
    const float* __restrict__ ba, const float* __restrict__ Va,
    const float* __restrict__ bva, const float* __restrict__ b_hh,
    const unsigned short* __restrict__ uk_b, const unsigned short* __restrict__ wa_p,
    const unsigned short* __restrict__ wih2_p, const unsigned short* __restrict__ whh_p,
    const float* __restrict__ E, unsigned short* __restrict__ hs_b,
    float* __restrict__ out_hlast, float* __restrict__ out_attn,
    const float* __restrict__ Wout, unsigned short* __restrict__ wout_b){
  __shared__ __align__(16) unsigned short uk_lds[Sz][Hz];   // 32KB
  __shared__ __align__(16) unsigned short enc_lds[Sz][Hz];  // 32KB
  __shared__ __align__(16) float h_lds[Hz];
  __shared__ __align__(16) float ctx_lds[Hz];
  __shared__ __align__(16) float redq[2][Hz];               // 2KB (q partials, then ctx partials)
  __shared__ __align__(16) float redh_a[2][Hz];             // 2KB (Whh.h partials, live whole step)
  __shared__ __align__(16) float redh[2][Hz];               // 2KB (Wih2.ctx partials)
  __shared__ float sc_lds[Sz];
  __shared__ float attn_lds[Sz];
  int tid = threadIdx.x;

  if (blockIdx.x >= Bz){
    // ---- Wout f32 -> bf16 streaming conversion (1024 blocks x 512 thr) ----
    int i = (blockIdx.x - Bz)*512 + tid;
    const int stride = 1024*512;
    for (int idx = i; idx < Vz*Hz; idx += stride) wout_b[idx] = f2bf(Wout[idx]);
    return;
  }

  int b = blockIdx.x;
  int k = tid & 255, qd = tid >> 8;       // output index, K-half (0/1)
  int lane = tid & 63, wv = tid >> 6;     // lane, wave 0..7
  const int rot = (b & 3) << 2;           // stagger offset: {0,4,8,12} jb-groups

  { // stage uk[b] (bf16, 32KB) into LDS
    const uint4* src = (const uint4*)(uk_b + (size_t)b*Sz*Hz);
    uint4* dst = (uint4*)(&uk_lds[0][0]);
    #pragma unroll
    for (int i=0;i<4;i++) dst[i*512+tid] = src[i*512+tid];
  }
  { // stage enc[b] f32 -> bf16 LDS
    const float4* src = (const float4*)(enc + (size_t)b*Sz*Hz);
    #pragma unroll
    for (int i=0;i<8;i++){
      int idx = i*512 + tid;              // 0..4095 float4s
      float4 v = src[idx];
      ushort4 p; p.x=f2bf(v.x); p.y=f2bf(v.y); p.z=f2bf(v.z); p.w=f2bf(v.w);
      *(ushort4*)((unsigned short*)(&enc_lds[0][0]) + idx*4) = p;
    }
  }
  if (tid < Hz) h_lds[tid] = ench[b*Hz + tid];
  float va_r[4], ba4[4];
  #pragma unroll
  for (int c=0;c<4;c++){ va_r[c] = Va[lane + 64*c]; ba4[c] = ba[lane + 64*c]; }
  float bhh_k = b_hh[k], bva_s = bva[0];

  // packed weight pointers, pre-offset: element (jb_local) at [jb*256 + k]
  const uint4* wap = (const uint4*)(wa_p)   + (size_t)qd*16*256 + k;
  const uint4* whp = (const uint4*)(whh_p)  + (size_t)qd*16*256 + k;
  const uint4* w2p = (const uint4*)(wih2_p) + (size_t)qd*16*256 + k;
  __syncthreads();

  for (int t=0; t<Tz; t++){
    int m = b*Tz + t;
    const float* hb = &h_lds[qd*128];
    // ---- phase A: both h-GEMVs (q = Wa.h, hh = Whh.h) — separate loops (no spill),
    //      jb-group order rotated per block to spread L2 line pressure
    {
      float a0=0.f, a1=0.f, a2=0.f, a3=0.f;
      #pragma unroll 2
      for (int jx=0;jx<16;jx+=4){
        int jj = (jx + rot) & 15;
        uint4 w0=wap[(jj+0)*256], w1=wap[(jj+1)*256], w2=wap[(jj+2)*256], w3=wap[(jj+3)*256];
        a0 += dot8(w0, hb + jj*8 +  0);
        a1 += dot8(w1, hb + jj*8 +  8);
        a2 += dot8(w2, hb + jj*8 + 16);
        a3 += dot8(w3, hb + jj*8 + 24);
      }
      redq[qd][k] = (a0+a1) + (a2+a3);
      float b0=0.f, b1=0.f, b2=0.f, b3=0.f;
      #pragma unroll 2
      for (int jx=0;jx<16;jx+=4){
        int jj = (jx + rot) & 15;
        uint4 w0=whp[(jj+0)*256], w1=whp[(jj+1)*256], w2=whp[(jj+2)*256], w3=whp[(jj+3)*256];
        b0 += dot8(w0, hb + jj*8 +  0);
        b1 += dot8(w1, hb + jj*8 +  8);
        b2 += dot8(w2, hb + jj*8 + 16);
        b3 += dot8(w3, hb + jj*8 + 24);
      }
      redh_a[qd][k] = (b0+b1) + (b2+b3);
    }
    // E-prefetch: consumed 5 phases later in the combine
    float e_pre = E[(size_t)m*Hz + k];
    __syncthreads();
    // ---- phase B: scores[s]; q reduction inlined (no intermediate barrier)
    {
      float ql[4];
      #pragma unroll
      for (int c=0;c<4;c++){
        int p = lane + 64*c;
        ql[c] = redq[0][p] + redq[1][p] + ba4[c];
      }
      #pragma unroll
      for (int si=0; si<8; si++){
        int s = wv*8 + si;
        float p = 0.f;
        #pragma unroll
        for (int c=0;c<4;c++){
          float u = bf2f(uk_lds[s][lane + 64*c]);
          p += ftanh(ql[c] + u) * va_r[c];
        }
        #pragma unroll
        for (int off=1; off<64; off<<=1) p += __shfl_xor(p, off, 64);
        if (lane==0) sc_lds[s] = p + bva_s;
      }
    }
    __syncthreads();
    // ---- phase C: softmax over s (each wave redundant; 1 exp/thread)
    {
      float sv = sc_lds[lane];
      float mx = sv;
      #pragma unroll
      for (int off=1; off<64; off<<=1) mx = fmaxf(mx, __shfl_xor(mx, off, 64));
      float e = __expf(sv - mx);
      float sum = e;
      #pragma unroll
      for (int off=1; off<64; off<<=1) sum += __shfl_xor(sum, off, 64);
      float a = e / sum;
      if (wv == 0){
        attn_lds[lane] = a;
        out_attn[(size_t)m*Sz + lane] = a;
      }
    }
    __syncthreads();
    // ---- phase D: ctx[k] = sum_s attn[s]*enc[b,s,k]  (s-split over qd)
    {
      float c0=0.f, c1=0.f;
      #pragma unroll
      for (int i=0;i<32;i+=2){
        int s = qd*32 + i;
        c0 += attn_lds[s]   * bf2f(enc_lds[s][k]);
        c1 += attn_lds[s+1] * bf2f(enc_lds[s+1][k]);
      }
      redq[qd][k] = c0 + c1;
    }
    __syncthreads();
    if (qd == 0) ctx_lds[k] = redq[0][k] + redq[1][k];
    __syncthreads();
    // ---- phase E: Wih2.ctx (rotated)
    {
      const float* cb = &ctx_lds[qd*128];
      float a0=0.f, a1=0.f, a2=0.f, a3=0.f;
      #pragma unroll 2
      for (int jx=0;jx<16;jx+=4){
        int jj = (jx + rot) & 15;
        uint4 w0=w2p[(jj+0)*256], w1=w2p[(jj+1)*256], w2=w2p[(jj+2)*256], w3=w2p[(jj+3)*256];
        a0 += dot8(w0, cb + jj*8 +  0);
        a1 += dot8(w1, cb + jj*8 +  8);
        a2 += dot8(w2, cb + jj*8 + 16);
        a3 += dot8(w3, cb + jj*8 + 24);
      }
      redh[qd][k] = (a0+a1) + (a2+a3);
    }
    __syncthreads();
    // ---- combine: hh reduction inlined (redh_a from phase A still live)
    if (qd == 0){
      float acc = e_pre + bhh_k
                + redh_a[0][k] + redh_a[1][k]
                + redh[0][k]   + redh[1][k];
      float hn = ftanh(acc);
      h_lds[k] = hn;
      hs_b[(size_t)m*Hz + k] = f2bf(hn);
      if (t==Tz-1) out_hlast[b*Hz + k] = hn;
    }
    __syncthreads();
  }
}

// ---------------- big GEMM: C[m][v] = hs[m,:].Wout[v,:] + b_out[v] ----------------
// R11 structure + occupancy bump: __launch_bounds__(256,4) -> VGPR<=128,
// 4 blocks/CU co-resident (more inter-block wave overlap to hide the per-K-step
// vmcnt(0) barrier drains). b_out loads hoisted out of the epilogue loops.
__global__ __launch_bounds__(256, 4) void k_gemm(
    const unsigned short* __restrict__ Ab, const unsigned short* __restrict__ Bb,
    const float* __restrict__ b_out, const float* __restrict__ lse,
    float* __restrict__ out, float* __restrict__ partials){
  __shared__ __align__(16) unsigned short As[128*64];
  __shared__ __align__(16) unsigned short Bs[128*64];
  int tid = threadIdx.x;
  int fid = blockIdx.x;               // 0..5499
  int xcd = fid & 7, wu = fid >> 3;   // hardware round-robins consecutive ids over 8 XCDs
  int wid = (xcd < 4 ? xcd*688 : 4*688 + (xcd-4)*687) + wu;  // bijective chunked
  int bn = wid / 22;                  // 0..249  (bn-major: 22 consecutive wids share bn)
  int bm = wid - bn*22;               // 0..21
  int m0 = bm*128, n0 = bn*128;
  int w = tid>>6, lane = tid&63;
  int wm = w>>1, wn = w&1;
  f32x4 acc[4][4];
  #pragma unroll
  for (int i=0;i<4;i++)
    #pragma unroll
    for (int j=0;j<4;j++) acc[i][j] = (f32x4){0.f,0.f,0.f,0.f};

  for (int ktx=0; ktx<4; ktx++){
    int kt = (ktx + bm) & 3;          // staggered K-step order
    __syncthreads();
    // async stage: per wave-instr, 64 lanes x 16B -> 1KB contiguous LDS
    #pragma unroll
    for (int i=0;i<4;i++){
      int chunk = i*256 + tid;          // = (i*256 + w*64) + lane
      int row = chunk>>3, c8 = chunk&7;
      gll16(Ab + (size_t)(m0+row)*Hz + kt*64 + c8*8, &As[(i*256 + w*64)*8]);
      gll16(Bb + (size_t)(n0+row)*Hz + kt*64 + c8*8, &Bs[(i*256 + w*64)*8]);
    }
    __syncthreads();
    #pragma unroll
    for (int ks=0; ks<2; ks++){
      bf16x8 af[4], bg[4];
      #pragma unroll
      for (int i=0;i<4;i++){
        int row = wm*64 + i*16 + (lane&15);
        af[i] = *(const bf16x8*)(&As[row*64 + ks*32 + (lane>>4)*8]);
      }
      #pragma unroll
      for (int j=0;j<4;j++){
        int row = wn*64 + j*16 + (lane&15);
        bg[j] = *(const bf16x8*)(&Bs[row*64 + ks*32 + (lane>>4)*8]);
      }
      #pragma unroll
      for (int i=0;i<4;i++)
        #pragma unroll
        for (int j=0;j<4;j++)
          acc[i][j] = __builtin_amdgcn_mfma_f32_16x16x32_bf16(af[i], bg[j], acc[i][j], 0,0,0);
    }
  }
  int col_l = lane & 15, rgrp = lane >> 4;
  // hoist b_out loads: col_j depends only on j (was redundantly loaded 16x)
  float bj[4];
  #pragma unroll
  for (int j=0;j<4;j++) bj[j] = b_out[n0 + wn*64 + j*16 + col_l];
  if (lse == nullptr){
    #pragma unroll
    for (int i=0;i<4;i++){
      int rowbase = m0 + wm*64 + i*16 + rgrp*4;
      #pragma unroll
      for (int r=0;r<4;r++){
        float se = 0.f;
        #pragma unroll
        for (int j=0;j<4;j++) se += __expf(acc[i][j][r] + bj[j]);
        se += __shfl_xor(se,1,64); se += __shfl_xor(se,2,64);
        se += __shfl_xor(se,4,64); se += __shfl_xor(se,8,64);
        if (col_l == 0) partials[(size_t)(bn*2+wn)*Mz + rowbase + r] = se;
      }
    }
  } else {
    #pragma unroll
    for (int i=0;i<4;i++){
      int rowbase = m0 + wm*64 + i*16 + rgrp*4;
      #pragma unroll
      for (int r=0;r<4;r++){
        float l = lse[rowbase + r];
        #pragma unroll
        for (int j=0;j<4;j++){
          int col = n0 + wn*64 + j*16 + col_l;
          out[(size_t)(rowbase+r)*Vz + col] = acc[i][j][r] + bj[j] - l;
        }
      }
    }
  }
}

__global__ __launch_bounds__(256) void k_lse(const float* __restrict__ partials,
                                             float* __restrict__ lse){
  int m = blockIdx.x*256 + threadIdx.x;
  if (m < Mz){
    float s = 0.f;
    for (int c=0;c<500;c++) s += partials[(size_t)c*Mz + m];
    lse[m] = logf(s);
  }
}

extern "C" void kernel_launch(void* const* d_in, const int* in_sizes, int n_in,
                              void* d_out, int out_size, void* d_ws, size_t ws_size,
                              hipStream_t stream) {
  const float* enc   = (const float*)d_in[0];
  const float* ench  = (const float*)d_in[1];
  const int*   target= (const int*)d_in[2];
  const float* emb   = (const float*)d_in[3];
  const float* Wa    = (const float*)d_in[4];
  const float* ba    = (const float*)d_in[5];
  const float* Ua    = (const float*)d_in[6];
  const float* bua   = (const float*)d_in[7];
  const float* Va    = (const float*)d_in[8];
  const float* bva   = (const float*)d_in[9];
  const float* Wih   = (const float*)d_in[10];
  const float* bih   = (const float*)d_in[11];
  const float* Whh   = (const float*)d_in[12];
  const float* bhh   = (const float*)d_in[13];
  const float* Wout  = (const float*)d_in[14];
  const float* bout  = (const float*)d_in[15];

  float* out = (float*)d_out;
  float* out_logits = out;                              // [2816][32000]
  float* out_hlast  = out + (size_t)Mz*Vz;              // [256][256]
  float* out_attn   = out_hlast + Bz*Hz;                // [2816][64]

  // ws layout: bf16 W_out + small packed bf16 weights + hs + lse
  char* ws = (char*)d_ws;
  unsigned short* wout_b = (unsigned short*)(ws);                 // 16,384,000 B
  unsigned short* wa_p   = (unsigned short*)(ws + 16384000);      // 131,072
  unsigned short* wih2_p = (unsigned short*)(ws + 16515072);      // 131,072
  unsigned short* whh_p  = (unsigned short*)(ws + 16646144);      // 131,072
  unsigned short* hs_b   = (unsigned short*)(ws + 16777216);      // 1,441,792
  float*          lse    = (float*)(ws + 18219008);               // 11,264

  // bulky transients live in the (not-yet-written) logits region of d_out:
  // uk (8,388,608 B) | E (2,883,584 B) | partials (5,632,000 B) — all dead before pass-2 writes
  char* sc = (char*)d_out;
  unsigned short* uk_b     = (unsigned short*)(sc);
  float*          E        = (float*)(sc + 8388608);
  float*          partials = (float*)(sc + 11272192);

  k_prep <<<256+176+1024, 256, 0, stream>>>(Wa, Wih, Whh,
                                            target, emb, bih, enc, Ua, bua,
                                            wa_p, wih2_p, whh_p, E, uk_b);
  k_rnn  <<<Bz+1024, 512, 0, stream>>>(enc, ench, ba, Va, bva, bhh,
                                       uk_b, wa_p, wih2_p, whh_p, E, hs_b,
                                       out_hlast, out_attn, Wout, wout_b);
  k_gemm <<<5500, 256, 0, stream>>>(hs_b, wout_b, bout, nullptr, out_logits, partials);
  k_lse  <<<11, 256, 0, stream>>>(partials, lse);
  k_gemm <<<5500, 256, 0, stream>>>(hs_b, wout_b, bout, lse, out_logits, partials);
}